// Round 3
// 4695.115 us; speedup vs baseline: 1.2116x; 1.2116x over previous
//
#include <hip/hip_runtime.h>
#include <hip/hip_cooperative_groups.h>
#include <math.h>

namespace cg = cooperative_groups;

#define NB   256      // persistent blocks (1 per CU)
#define NT   256      // threads per block (4 waves)
#define BSZ  512      // batch
#define HSZ  512      // hidden
#define LSEQ 256      // sequence length
#define G3H  1536

typedef __attribute__((ext_vector_type(8))) short sh8;   // 8 bf16 = one MFMA frag
typedef __attribute__((ext_vector_type(4))) float f4;    // MFMA acc

#define MFMA(a,b,c) __builtin_amdgcn_mfma_f32_16x16x32_bf16((a),(b),(c),0,0,0)
#define AGENT __HIP_MEMORY_SCOPE_AGENT
#define WGRP  __HIP_MEMORY_SCOPE_WORKGROUP
#define RLX   __ATOMIC_RELAXED

__device__ __forceinline__ float bf2f(unsigned short u) {
    union { unsigned int i; float f; } v; v.i = ((unsigned int)u) << 16; return v.f;
}
__device__ __forceinline__ unsigned short f2bf(float f) {
    union { float f; unsigned int i; } v; v.f = f;
    unsigned int r = v.i + 0x7fffu + ((v.i >> 16) & 1u);   // RNE
    return (unsigned short)(r >> 16);
}
__device__ __forceinline__ float sigm(float v) { return 1.f / (1.f + __expf(-v)); }
__device__ __forceinline__ float tanh_(float v) { return 1.f - 2.f / (1.f + __expf(2.f * v)); }

__device__ __forceinline__ int xcc_id() {
    int x;
    asm volatile("s_getreg_b32 %0, hwreg(HW_REG_XCC_ID)" : "=s"(x));
    return x & 7;
}

struct P {
    const float *z1, *y, *x, *h1;
    const float *w_ih1, *w_hh1, *b_ih1, *b_hh1;
    const float *w_ih2, *w_hh2, *b_ih2, *b_hh2;
    const float *w_fc, *b_fc;
    unsigned short *wb1, *wb2, *wbI;        // bf16 weights [1536][512]
    unsigned short *giy;                     // bf16 [512][1536]
    unsigned short *s0h[2], *s0l[2];         // bf16 hi/lo state ping-pong [512][512]
    unsigned short *s1h[2], *s1l[2];
    float *accT;                             // [256][512]
    unsigned *bar;                           // 8 groups x 512 u32 barrier region
    unsigned *claim;                         // 8 per-XCD slot counters
    float *out;                              // [512][256]
};

// ---------------- init kernel (kernel-boundary flush publishes all of this) ------
__global__ __launch_bounds__(256) void init_k(P p)
{
    int gt = blockIdx.x * 256 + threadIdx.x;
    int stride = gridDim.x * 256;
    for (int i = gt; i < G3H * HSZ; i += stride) {
        p.wb1[i] = f2bf(p.w_hh1[i]);
        p.wb2[i] = f2bf(p.w_hh2[i]);
        p.wbI[i] = f2bf(p.w_ih2[i]);
    }
    for (int i = gt; i < BSZ * HSZ; i += stride) {
        int b = i >> 9, hh = i & 511;
        float v0 = (hh < 385) ? p.z1[b * 385 + hh] : p.y[b * 127 + (hh - 385)];
        unsigned short u = f2bf(v0);
        p.s0h[0][i] = u; p.s0l[0][i] = f2bf(v0 - bf2f(u));
        float v1 = p.h1[i];
        u = f2bf(v1);
        p.s1h[0][i] = u; p.s1l[0][i] = f2bf(v1 - bf2f(u));
    }
    for (int i = gt; i < LSEQ * BSZ; i += stride) p.accT[i] = 0.f;
    for (int i = gt; i < 8 * 512; i += stride) p.bar[i] = 0u;
    for (int i = gt; i < 8; i += stride) p.claim[i] = 0u;
    for (int i = gt; i < BSZ * G3H; i += stride) {
        int b = i / G3H, j = i - b * G3H;
        float a = p.b_ih1[j];
        const float* yr = p.y + b * 127;
        const float* wr = p.w_ih1 + j * 128 + 1;
        #pragma unroll 4
        for (int k = 0; k < 127; ++k) a += yr[k] * wr[k];
        p.giy[i] = f2bf(a);
    }
}

// Batched scan of all 8 sub-lines in ONE round-trip. Each op is the EXACT
// R7-proven poll_rmw form (global_atomic_add vdst, vaddr, 0 sc0 — returns old,
// executes at XCD L2, never stale-L1). 8 explicit address pairs; single
// vmcnt(0) drain -> ~1 RTT per poll round (vs the old combiner's 8 serialized
// RTTs + flag hop + sleep(4)-backoff detection).
__device__ __forceinline__ bool scan8p(unsigned* l0, unsigned* l1, unsigned* l2, unsigned* l3,
                                       unsigned* l4, unsigned* l5, unsigned* l6, unsigned* l7,
                                       unsigned tgt)
{
    unsigned r0, r1, r2, r3, r4, r5, r6, r7;
    unsigned z = 0;
    asm volatile(
        "global_atomic_add %0, %8, %16, off sc0\n\t"
        "global_atomic_add %1, %9, %16, off sc0\n\t"
        "global_atomic_add %2, %10, %16, off sc0\n\t"
        "global_atomic_add %3, %11, %16, off sc0\n\t"
        "global_atomic_add %4, %12, %16, off sc0\n\t"
        "global_atomic_add %5, %13, %16, off sc0\n\t"
        "global_atomic_add %6, %14, %16, off sc0\n\t"
        "global_atomic_add %7, %15, %16, off sc0\n\t"
        "s_waitcnt vmcnt(0)"
        : "=&v"(r0), "=&v"(r1), "=&v"(r2), "=&v"(r3),
          "=&v"(r4), "=&v"(r5), "=&v"(r6), "=&v"(r7)
        : "v"(l0), "v"(l1), "v"(l2), "v"(l3),
          "v"(l4), "v"(l5), "v"(l6), "v"(l7), "v"(z)
        : "memory");
    return (r0 >= tgt) & (r1 >= tgt) & (r2 >= tgt) & (r3 >= tgt)
         & (r4 >= tgt) & (r5 >= tgt) & (r6 >= tgt) & (r7 >= tgt);
}

// Monolithic barrier, IDENTICAL placement/semantics to the proven kernel.
// Only the fast-path WAIT mechanism changed: every block scans all 8 sub-lines
// directly (batched, 1 RTT/round) instead of combiner+flag. Counters are
// cumulative and monotone; add-0 RMW polls cannot perturb them, so the barrier
// cannot open early regardless of inter-block skew.
__device__ __forceinline__ void gbar(unsigned* gb, int hx, unsigned bno, bool fast)
{
    __syncthreads();   // all waves drain vmcnt(0): stores committed in XCD L2
    if (threadIdx.x == 0) {
        if (fast) {
            __hip_atomic_fetch_add(gb + (hx & 7) * 32, 1u, RLX, WGRP);
            unsigned tgt = 4u * bno;
            long g = 0;
            while (!scan8p(gb, gb + 32, gb + 64, gb + 96,
                           gb + 128, gb + 160, gb + 192, gb + 224, tgt)) {
                __builtin_amdgcn_s_sleep(1);
                if (++g > (1L << 24)) break;
            }
        } else {
            __hip_atomic_fetch_add(gb, 1u, __ATOMIC_RELEASE, AGENT);
            while (__hip_atomic_load(gb, RLX, AGENT) < 32u * bno)
                __builtin_amdgcn_s_sleep(1);
            __builtin_amdgcn_fence(__ATOMIC_ACQUIRE, "agent");
        }
    }
    __syncthreads();
    if (fast) {
        // invalidate this CU's L1 so post-barrier loads see the group's L2 data
        asm volatile("buffer_inv sc0\n\ts_waitcnt vmcnt(0)" ::: "memory");
    }
}

__global__ __launch_bounds__(NT, 1) void rnn_kernel(P p)
{
    // ALL 9 weight matrices for this block's 16 h-cols live in LDS (146 KB):
    // 0-2: w_hh1 r/z/n   3-5: w_ih2 r/z/n   6-8: w_hh2 r/z/n
    __shared__ __align__(16) unsigned short W[9][16][520];
    __shared__ int s_xcd, s_slot;

    cg::grid_group grid = cg::this_grid();
    const int tid  = threadIdx.x;
    const int bid  = blockIdx.x;

    // ---- runtime XCD-local group formation ----
    if (tid == 0) {
        int x = xcc_id();
        s_xcd = x;
        s_slot = (int)__hip_atomic_fetch_add(&p.claim[x], 1u, RLX, AGENT);
    }
    grid.sync();   // one-time full-coherence rendezvous (claims all visible)

    bool fast = true;
    #pragma unroll
    for (int x = 0; x < 8; ++x)
        fast = fast && (__hip_atomic_load(&p.claim[x], RLX, AGENT) == 32u);

    const int by = fast ? s_xcd  : (bid >> 5);   // batch group (8)
    const int hx = fast ? s_slot : (bid & 31);   // h tile within group (32)

    const int lane = tid & 63, w = tid >> 6;
    const int m = lane & 15, quad = lane >> 4;
    const int h0 = hx * 16, b0 = by * 64 + w * 16;
    const int h  = h0 + m;
    const int bA = b0 + m;
    const int bD = b0 + quad * 4;
    unsigned* gb = p.bar + by * 512;

    // stage all 9 weight matrices into LDS
    for (int c = tid; c < 9 * 1024; c += NT) {
        int mat = c >> 10, rem = c & 1023;
        int lc = rem >> 6, ch = rem & 63;
        const unsigned short* base =
            (mat < 3) ? (p.wb1 + (size_t)(mat * HSZ + h0 + lc) * HSZ)
          : (mat < 6) ? (p.wbI + (size_t)((mat - 3) * HSZ + h0 + lc) * HSZ)
                      : (p.wb2 + (size_t)((mat - 6) * HSZ + h0 + lc) * HSZ);
        *(sh8*)&W[mat][lc][ch * 8] = *((const sh8*)base + ch);
    }
    __syncthreads();

    const float bfc = p.b_fc[0];
    const int hq0 = h, hq1 = HSZ + h, hq2 = 2 * HSZ + h;
    const float bh1v0 = p.b_hh1[hq0], bh1v1 = p.b_hh1[hq1], bh1v2 = p.b_hh1[hq2];
    const float bi2v0 = p.b_ih2[hq0], bi2v1 = p.b_ih2[hq1], bi2v2 = p.b_ih2[hq2];
    const float bh2v0 = p.b_hh2[hq0], bh2v1 = p.b_hh2[hq1], bh2v2 = p.b_hh2[hq2];
    const float w0c0 = p.w_ih1[(size_t)hq0 * 128];
    const float w0c1 = p.w_ih1[(size_t)hq1 * 128];
    const float w0c2 = p.w_ih1[(size_t)hq2 * 128];
    const float wfcv = p.w_fc[h];

    float gyv[4][3];
    #pragma unroll
    for (int r = 0; r < 4; ++r) {
        gyv[r][0] = bf2f(p.giy[(size_t)(bD + r) * G3H + hq0]);
        gyv[r][1] = bf2f(p.giy[(size_t)(bD + r) * G3H + hq1]);
        gyv[r][2] = bf2f(p.giy[(size_t)(bD + r) * G3H + hq2]);
    }

    unsigned bno = 0;

    #pragma clang loop unroll(disable)
    for (int t = 0; t < LSEQ; ++t) {
        const int pi = t & 1, po = pi ^ 1;

        // ---------- phase A: gh1 = s0 @ w_hh1^T (weights LDS), GRU1 -> s0_new ----------
        {
            const unsigned short* sh_ = p.s0h[pi];
            const unsigned short* sl_ = p.s0l[pi];
            const sh8* Ah = (const sh8*)sh_ + (size_t)bA * 64;
            const sh8* Al = (const sh8*)sl_ + (size_t)bA * 64;
            sh8 ah[16], al[16];
            #pragma unroll
            for (int ks = 0; ks < 16; ++ks) { ah[ks] = Ah[ks * 4 + quad]; al[ks] = Al[ks * 4 + quad]; }
            f4 a0 = {0.f,0.f,0.f,0.f}, a1 = a0, a2 = a0;
            #pragma unroll
            for (int ks = 0; ks < 16; ++ks) {
                const int fo = (ks * 4 + quad) * 8;
                sh8 w_r = *(const sh8*)&W[0][m][fo];
                sh8 w_z = *(const sh8*)&W[1][m][fo];
                sh8 w_n = *(const sh8*)&W[2][m][fo];
                a0 = MFMA(ah[ks], w_r, a0); a0 = MFMA(al[ks], w_r, a0);
                a1 = MFMA(ah[ks], w_z, a1); a1 = MFMA(al[ks], w_z, a1);
                a2 = MFMA(ah[ks], w_n, a2); a2 = MFMA(al[ks], w_n, a2);
            }
            unsigned short* oh = p.s0h[po];
            unsigned short* ol = p.s0l[po];
            #pragma unroll
            for (int r = 0; r < 4; ++r) {
                int b = bD + r;
                float o;
                if (t == 0) o = p.x[b];
                else {
                    float av = fast ? p.accT[(t - 1) * BSZ + b]
                                    : __hip_atomic_load(&p.accT[(t - 1) * BSZ + b], RLX, AGENT);
                    o = fmaxf(av + bfc, 0.f);
                }
                float rr = sigm(gyv[r][0] + o * w0c0 + a0[r] + bh1v0);
                float zz = sigm(gyv[r][1] + o * w0c1 + a1[r] + bh1v1);
                float nn = tanh_(gyv[r][2] + o * w0c2 + rr * (a2[r] + bh1v2));
                size_t ix = (size_t)b * HSZ + h;
                float so = bf2f(sh_[ix]) + bf2f(sl_[ix]);
                float sn = (1.f - zz) * nn + zz * so;
                unsigned short u = f2bf(sn);
                oh[ix] = u; ol[ix] = f2bf(sn - bf2f(u));
            }
        }
        ++bno; gbar(gb, hx, bno, fast);

        // ---------- phase B: gi2 = s0_new @ w_ih2^T, gh2 = s1 @ w_hh2^T (LDS), GRU2 + fc ----
        {
            const unsigned short* sh_ = p.s1h[pi];
            const unsigned short* sl_ = p.s1l[pi];
            const sh8* Aih = (const sh8*)p.s0h[po] + (size_t)bA * 64;
            const sh8* Ail = (const sh8*)p.s0l[po] + (size_t)bA * 64;
            const sh8* Ahh = (const sh8*)sh_ + (size_t)bA * 64;
            const sh8* Ahl = (const sh8*)sl_ + (size_t)bA * 64;

            sh8 ih[16], il[16];
            #pragma unroll
            for (int ks = 0; ks < 16; ++ks) { ih[ks] = Aih[ks * 4 + quad]; il[ks] = Ail[ks * 4 + quad]; }
            f4 ci0 = {0.f,0.f,0.f,0.f}, ci1 = ci0, ci2 = ci0;
            #pragma unroll
            for (int ks = 0; ks < 16; ++ks) {
                const int fo = (ks * 4 + quad) * 8;
                sh8 wir = *(const sh8*)&W[3][m][fo];
                sh8 wiz = *(const sh8*)&W[4][m][fo];
                sh8 win = *(const sh8*)&W[5][m][fo];
                ci0 = MFMA(ih[ks], wir, ci0); ci0 = MFMA(il[ks], wir, ci0);
                ci1 = MFMA(ih[ks], wiz, ci1); ci1 = MFMA(il[ks], wiz, ci1);
                ci2 = MFMA(ih[ks], win, ci2); ci2 = MFMA(il[ks], win, ci2);
            }
            sh8 hh[16], hl[16];
            #pragma unroll
            for (int ks = 0; ks < 16; ++ks) { hh[ks] = Ahh[ks * 4 + quad]; hl[ks] = Ahl[ks * 4 + quad]; }
            f4 ch0 = {0.f,0.f,0.f,0.f}, ch1 = ch0, ch2 = ch0;
            #pragma unroll
            for (int ks = 0; ks < 16; ++ks) {
                const int fo = (ks * 4 + quad) * 8;
                sh8 whr = *(const sh8*)&W[6][m][fo];
                sh8 whz = *(const sh8*)&W[7][m][fo];
                sh8 whn = *(const sh8*)&W[8][m][fo];
                ch0 = MFMA(hh[ks], whr, ch0); ch0 = MFMA(hl[ks], whr, ch0);
                ch1 = MFMA(hh[ks], whz, ch1); ch1 = MFMA(hl[ks], whz, ch1);
                ch2 = MFMA(hh[ks], whn, ch2); ch2 = MFMA(hl[ks], whn, ch2);
            }
            unsigned short* oh = p.s1h[po];
            unsigned short* ol = p.s1l[po];
            #pragma unroll
            for (int r = 0; r < 4; ++r) {
                int b = bD + r;
                float rr = sigm(ci0[r] + bi2v0 + ch0[r] + bh2v0);
                float zz = sigm(ci1[r] + bi2v1 + ch1[r] + bh2v1);
                float nn = tanh_(ci2[r] + bi2v2 + rr * (ch2[r] + bh2v2));
                size_t ix = (size_t)b * HSZ + h;
                float so = bf2f(sh_[ix]) + bf2f(sl_[ix]);
                float sn = (1.f - zz) * nn + zz * so;
                unsigned short u = f2bf(sn);
                oh[ix] = u; ol[ix] = f2bf(sn - bf2f(u));
                float c = sn * wfcv;
                c += __shfl_xor(c, 1); c += __shfl_xor(c, 2);
                c += __shfl_xor(c, 4); c += __shfl_xor(c, 8);
                if (m == 0) {
                    if (fast) __hip_atomic_fetch_add(&p.accT[t * BSZ + b], c, RLX, WGRP);
                    else      atomicAdd(&p.accT[t * BSZ + b], c);
                }
            }
        }
        ++bno; gbar(gb, hx, bno, fast);
    }

    // ---------- epilogue: group-local out write (follows final gbar + L1-inv) ----------
    {
        const int r = hx;
        for (int e = tid; e < 512; e += NT) {
            int idx = r * 512 + e;
            int bl = idx >> 8, t = idx & 255;
            int b = by * 64 + bl;
            float av = fast ? p.accT[t * BSZ + b]
                            : __hip_atomic_load(&p.accT[t * BSZ + b], RLX, AGENT);
            p.out[(size_t)b * 256 + t] = fmaxf(av + bfc, 0.f);
        }
    }
}

extern "C" void kernel_launch(void* const* d_in, const int* in_sizes, int n_in,
                              void* d_out, int out_size, void* d_ws, size_t ws_size,
                              hipStream_t stream)
{
    (void)in_sizes; (void)n_in; (void)out_size; (void)ws_size;
    P p;
    p.z1    = (const float*)d_in[0];
    p.y     = (const float*)d_in[1];
    p.x     = (const float*)d_in[2];
    p.h1    = (const float*)d_in[3];
    p.w_ih1 = (const float*)d_in[4];
    p.w_hh1 = (const float*)d_in[5];
    p.b_ih1 = (const float*)d_in[6];
    p.b_hh1 = (const float*)d_in[7];
    p.w_ih2 = (const float*)d_in[8];
    p.w_hh2 = (const float*)d_in[9];
    p.b_ih2 = (const float*)d_in[10];
    p.b_hh2 = (const float*)d_in[11];
    p.w_fc  = (const float*)d_in[12];
    p.b_fc  = (const float*)d_in[13];

    unsigned short* ws = (unsigned short*)d_ws;
    size_t off = 0;
    p.wb1 = ws + off; off += (size_t)G3H * HSZ;
    p.wb2 = ws + off; off += (size_t)G3H * HSZ;
    p.wbI = ws + off; off += (size_t)G3H * HSZ;
    p.giy = ws + off; off += (size_t)BSZ * G3H;
    for (int i = 0; i < 2; ++i) { p.s0h[i] = ws + off; off += (size_t)BSZ * HSZ; }
    for (int i = 0; i < 2; ++i) { p.s0l[i] = ws + off; off += (size_t)BSZ * HSZ; }
    for (int i = 0; i < 2; ++i) { p.s1h[i] = ws + off; off += (size_t)BSZ * HSZ; }
    for (int i = 0; i < 2; ++i) { p.s1l[i] = ws + off; off += (size_t)BSZ * HSZ; }
    p.accT  = (float*)(ws + off);    off += (size_t)LSEQ * BSZ * 2;
    p.bar   = (unsigned*)(ws + off); off += 8 * 512 * 2;
    p.claim = (unsigned*)(ws + off);
    p.out   = (float*)d_out;

    init_k<<<dim3(1024), dim3(256), 0, stream>>>(p);

    void* args[] = { &p };
    hipLaunchCooperativeKernel((const void*)rnn_kernel, dim3(NB), dim3(NT), args, 0, stream);
}

// Round 5
// 4362.325 us; speedup vs baseline: 1.3040x; 1.0763x over previous
//
#include <hip/hip_runtime.h>
#include <hip/hip_cooperative_groups.h>
#include <math.h>

namespace cg = cooperative_groups;

#define NB   256      // persistent blocks (1 per CU)
#define NT   256      // threads per block (4 waves)
#define BSZ  512      // batch
#define HSZ  512      // hidden
#define LSEQ 256      // sequence length
#define G3H  1536

typedef __attribute__((ext_vector_type(8))) short sh8;   // 8 bf16 = one MFMA frag
typedef __attribute__((ext_vector_type(4))) float f4;    // MFMA acc

#define MFMA(a,b,c) __builtin_amdgcn_mfma_f32_16x16x32_bf16((a),(b),(c),0,0,0)
#define AGENT __HIP_MEMORY_SCOPE_AGENT
#define WGRP  __HIP_MEMORY_SCOPE_WORKGROUP
#define RLX   __ATOMIC_RELAXED

__device__ __forceinline__ float bf2f(unsigned short u) {
    union { unsigned int i; float f; } v; v.i = ((unsigned int)u) << 16; return v.f;
}
__device__ __forceinline__ unsigned short f2bf(float f) {
    union { float f; unsigned int i; } v; v.f = f;
    unsigned int r = v.i + 0x7fffu + ((v.i >> 16) & 1u);   // RNE
    return (unsigned short)(r >> 16);
}
__device__ __forceinline__ float sigm(float v) { return 1.f / (1.f + __expf(-v)); }
__device__ __forceinline__ float tanh_(float v) { return 1.f - 2.f / (1.f + __expf(2.f * v)); }

__device__ __forceinline__ int xcc_id() {
    int x;
    asm volatile("s_getreg_b32 %0, hwreg(HW_REG_XCC_ID)" : "=s"(x));
    return x & 7;
}

struct P {
    const float *z1, *y, *x, *h1;
    const float *w_ih1, *w_hh1, *b_ih1, *b_hh1;
    const float *w_ih2, *w_hh2, *b_ih2, *b_hh2;
    const float *w_fc, *b_fc;
    unsigned short *wb1, *wb2, *wbI;        // bf16 weights [1536][512]
    unsigned short *giy;                     // bf16 [512][1536]
    unsigned short *s0h[2], *s0l[2];         // bf16 hi/lo state ping-pong [512][512]
    unsigned short *s1h[2], *s1l[2];
    float *accT;                             // [256][512]
    unsigned *bar;                           // 8 groups x 512 u32 barrier region
    unsigned *claim;                         // 8 per-XCD slot counters
    float *out;                              // [512][256]
};

// ---------------- init kernel (kernel-boundary flush publishes all of this) ------
__global__ __launch_bounds__(256) void init_k(P p)
{
    int gt = blockIdx.x * 256 + threadIdx.x;
    int stride = gridDim.x * 256;
    for (int i = gt; i < G3H * HSZ; i += stride) {
        p.wb1[i] = f2bf(p.w_hh1[i]);
        p.wb2[i] = f2bf(p.w_hh2[i]);
        p.wbI[i] = f2bf(p.w_ih2[i]);
    }
    for (int i = gt; i < BSZ * HSZ; i += stride) {
        int b = i >> 9, hh = i & 511;
        float v0 = (hh < 385) ? p.z1[b * 385 + hh] : p.y[b * 127 + (hh - 385)];
        unsigned short u = f2bf(v0);
        p.s0h[0][i] = u; p.s0l[0][i] = f2bf(v0 - bf2f(u));
        float v1 = p.h1[i];
        u = f2bf(v1);
        p.s1h[0][i] = u; p.s1l[0][i] = f2bf(v1 - bf2f(u));
    }
    for (int i = gt; i < LSEQ * BSZ; i += stride) p.accT[i] = 0.f;
    for (int i = gt; i < 8 * 512; i += stride) p.bar[i] = 0u;
    for (int i = gt; i < 8; i += stride) p.claim[i] = 0u;
    for (int i = gt; i < BSZ * G3H; i += stride) {
        int b = i / G3H, j = i - b * G3H;
        float a = p.b_ih1[j];
        const float* yr = p.y + b * 127;
        const float* wr = p.w_ih1 + j * 128 + 1;
        #pragma unroll 4
        for (int k = 0; k < 127; ++k) a += yr[k] * wr[k];
        p.giy[i] = f2bf(a);
    }
}

// Batched scan of all 8 sub-lines in ONE round-trip. Each op is the R7-proven
// poll_rmw form (global_atomic_add vdst, vaddr, 0 sc0 — returns old, executes
// at XCD L2, never stale-L1). Proven sound in R3 (passed, -1.37ms).
__device__ __forceinline__ bool scan8p(unsigned* l0, unsigned* l1, unsigned* l2, unsigned* l3,
                                       unsigned* l4, unsigned* l5, unsigned* l6, unsigned* l7,
                                       unsigned tgt)
{
    unsigned r0, r1, r2, r3, r4, r5, r6, r7;
    unsigned z = 0;
    asm volatile(
        "global_atomic_add %0, %8, %16, off sc0\n\t"
        "global_atomic_add %1, %9, %16, off sc0\n\t"
        "global_atomic_add %2, %10, %16, off sc0\n\t"
        "global_atomic_add %3, %11, %16, off sc0\n\t"
        "global_atomic_add %4, %12, %16, off sc0\n\t"
        "global_atomic_add %5, %13, %16, off sc0\n\t"
        "global_atomic_add %6, %14, %16, off sc0\n\t"
        "global_atomic_add %7, %15, %16, off sc0\n\t"
        "s_waitcnt vmcnt(0)"
        : "=&v"(r0), "=&v"(r1), "=&v"(r2), "=&v"(r3),
          "=&v"(r4), "=&v"(r5), "=&v"(r6), "=&v"(r7)
        : "v"(l0), "v"(l1), "v"(l2), "v"(l3),
          "v"(l4), "v"(l5), "v"(l6), "v"(l7), "v"(z)
        : "memory");
    return (r0 >= tgt) & (r1 >= tgt) & (r2 >= tgt) & (r3 >= tgt)
         & (r4 >= tgt) & (r5 >= tgt) & (r6 >= tgt) & (r7 >= tgt);
}

// Split barrier pieces. gbar (monolithic) == R3-proven semantics exactly.
// Caller of gbar_arrive must have executed __syncthreads() first (drains
// vmcnt(0) per wave -> stores committed in XCD L2 before arrival visible).
__device__ __forceinline__ void gbar_arrive(unsigned* gb, int hx, bool fast)
{
    if (threadIdx.x == 0) {
        if (fast) __hip_atomic_fetch_add(gb + (hx & 7) * 32, 1u, RLX, WGRP);
        else      __hip_atomic_fetch_add(gb, 1u, __ATOMIC_RELEASE, AGENT);
    }
}
__device__ __forceinline__ void gbar_wait(unsigned* gb, unsigned bno, bool fast)
{
    if (threadIdx.x == 0) {
        if (fast) {
            unsigned tgt = 4u * bno;
            long g = 0;
            while (!scan8p(gb, gb + 32, gb + 64, gb + 96,
                           gb + 128, gb + 160, gb + 192, gb + 224, tgt)) {
                __builtin_amdgcn_s_sleep(1);
                if (++g > (1L << 24)) break;
            }
        } else {
            long g = 0;
            while (__hip_atomic_load(gb, RLX, AGENT) < 32u * bno) {
                __builtin_amdgcn_s_sleep(1);
                if (++g > (1L << 27)) break;
            }
            __builtin_amdgcn_fence(__ATOMIC_ACQUIRE, "agent");
        }
    }
    __syncthreads();
    if (fast) {
        // invalidate this CU's L1 so post-barrier loads see the group's L2 data
        asm volatile("buffer_inv sc0\n\ts_waitcnt vmcnt(0)" ::: "memory");
    }
}
__device__ __forceinline__ void gbar(unsigned* gb, int hx, unsigned bno, bool fast)
{
    __syncthreads();
    gbar_arrive(gb, hx, fast);
    gbar_wait(gb, bno, fast);
}

__global__ __launch_bounds__(NT, 1) void rnn_kernel(P p)
{
    // ALL 9 weight matrices for this block's 16 h-cols live in LDS (146 KB):
    // 0-2: w_hh1 r/z/n   3-5: w_ih2 r/z/n   6-8: w_hh2 r/z/n
    __shared__ __align__(16) unsigned short W[9][16][520];
    __shared__ int s_xcd, s_slot;

    cg::grid_group grid = cg::this_grid();
    const int tid  = threadIdx.x;
    const int bid  = blockIdx.x;

    // ---- runtime XCD-local group formation ----
    if (tid == 0) {
        int x = xcc_id();
        s_xcd = x;
        s_slot = (int)__hip_atomic_fetch_add(&p.claim[x], 1u, RLX, AGENT);
    }
    grid.sync();   // one-time full-coherence rendezvous (claims all visible)

    bool fast = true;
    #pragma unroll
    for (int x = 0; x < 8; ++x)
        fast = fast && (__hip_atomic_load(&p.claim[x], RLX, AGENT) == 32u);

    const int by = fast ? s_xcd  : (bid >> 5);   // batch group (8)
    const int hx = fast ? s_slot : (bid & 31);   // h tile within group (32)

    const int lane = tid & 63, w = tid >> 6;
    const int m = lane & 15, quad = lane >> 4;
    const int h0 = hx * 16, b0 = by * 64 + w * 16;
    const int h  = h0 + m;
    const int bA = b0 + m;
    const int bD = b0 + quad * 4;
    unsigned* gb = p.bar + by * 512;

    // stage all 9 weight matrices into LDS
    for (int c = tid; c < 9 * 1024; c += NT) {
        int mat = c >> 10, rem = c & 1023;
        int lc = rem >> 6, ch = rem & 63;
        const unsigned short* base =
            (mat < 3) ? (p.wb1 + (size_t)(mat * HSZ + h0 + lc) * HSZ)
          : (mat < 6) ? (p.wbI + (size_t)((mat - 3) * HSZ + h0 + lc) * HSZ)
                      : (p.wb2 + (size_t)((mat - 6) * HSZ + h0 + lc) * HSZ);
        *(sh8*)&W[mat][lc][ch * 8] = *((const sh8*)base + ch);
    }
    __syncthreads();

    const float bfc = p.b_fc[0];
    const int hq0 = h, hq1 = HSZ + h, hq2 = 2 * HSZ + h;
    const float bh1v0 = p.b_hh1[hq0], bh1v1 = p.b_hh1[hq1], bh1v2 = p.b_hh1[hq2];
    const float bi2v0 = p.b_ih2[hq0], bi2v1 = p.b_ih2[hq1], bi2v2 = p.b_ih2[hq2];
    const float bh2v0 = p.b_hh2[hq0], bh2v1 = p.b_hh2[hq1], bh2v2 = p.b_hh2[hq2];
    const float w0c0 = p.w_ih1[(size_t)hq0 * 128];
    const float w0c1 = p.w_ih1[(size_t)hq1 * 128];
    const float w0c2 = p.w_ih1[(size_t)hq2 * 128];
    const float wfcv = p.w_fc[h];

    float gyv[4][3];
    #pragma unroll
    for (int r = 0; r < 4; ++r) {
        gyv[r][0] = bf2f(p.giy[(size_t)(bD + r) * G3H + hq0]);
        gyv[r][1] = bf2f(p.giy[(size_t)(bD + r) * G3H + hq1]);
        gyv[r][2] = bf2f(p.giy[(size_t)(bD + r) * G3H + hq2]);
    }

    unsigned bno = 0;

    #pragma clang loop unroll(disable)
    for (int t = 0; t < LSEQ; ++t) {
        const int pi = t & 1, po = pi ^ 1;

        // ---------- phase A: gh1 = s0 @ w_hh1^T (weights LDS), GRU1 -> s0_new ----------
        {
            const unsigned short* sh_ = p.s0h[pi];
            const unsigned short* sl_ = p.s0l[pi];
            const sh8* Ah = (const sh8*)sh_ + (size_t)bA * 64;
            const sh8* Al = (const sh8*)sl_ + (size_t)bA * 64;
            sh8 ah[16], al[16];
            #pragma unroll
            for (int ks = 0; ks < 16; ++ks) { ah[ks] = Ah[ks * 4 + quad]; al[ks] = Al[ks * 4 + quad]; }
            f4 a0 = {0.f,0.f,0.f,0.f}, a1 = a0, a2 = a0;
            #pragma unroll
            for (int ks = 0; ks < 16; ++ks) {
                const int fo = (ks * 4 + quad) * 8;
                sh8 w_r = *(const sh8*)&W[0][m][fo];
                sh8 w_z = *(const sh8*)&W[1][m][fo];
                sh8 w_n = *(const sh8*)&W[2][m][fo];
                a0 = MFMA(ah[ks], w_r, a0); a0 = MFMA(al[ks], w_r, a0);
                a1 = MFMA(ah[ks], w_z, a1); a1 = MFMA(al[ks], w_z, a1);
                a2 = MFMA(ah[ks], w_n, a2); a2 = MFMA(al[ks], w_n, a2);
            }
            unsigned short* oh = p.s0h[po];
            unsigned short* ol = p.s0l[po];
            #pragma unroll
            for (int r = 0; r < 4; ++r) {
                int b = bD + r;
                float o;
                if (t == 0) o = p.x[b];
                else {
                    float av = fast ? p.accT[(t - 1) * BSZ + b]
                                    : __hip_atomic_load(&p.accT[(t - 1) * BSZ + b], RLX, AGENT);
                    o = fmaxf(av + bfc, 0.f);
                }
                float rr = sigm(gyv[r][0] + o * w0c0 + a0[r] + bh1v0);
                float zz = sigm(gyv[r][1] + o * w0c1 + a1[r] + bh1v1);
                float nn = tanh_(gyv[r][2] + o * w0c2 + rr * (a2[r] + bh1v2));
                size_t ix = (size_t)b * HSZ + h;
                float so = bf2f(sh_[ix]) + bf2f(sl_[ix]);
                float sn = (1.f - zz) * nn + zz * so;
                unsigned short u = f2bf(sn);
                oh[ix] = u; ol[ix] = f2bf(sn - bf2f(u));
            }
        }
        ++bno;
        __syncthreads();                      // drains vmcnt(0): s0_new in XCD L2
        gbar_arrive(gb, hx, fast);

        // ---------- bar1 window: gh2 = s1[pi] @ w_hh2^T. Inputs were published at
        // bar2(t-1) (s1[pi] last written in phase B(t-1), before its arrive), and
        // nothing touched s1 lines in this CU's L1 since bar2(t-1)'s buffer_inv.
        // Next writer (phase B(t+1)) runs after bar1(t+1)-wait, which transitively
        // requires every block to have passed bar2(t) -- i.e. after these reads.
        // Results (ch0..ch2, so1) ride in VGPRs across the wait.
        f4 ch0 = {0.f,0.f,0.f,0.f}, ch1 = ch0, ch2 = ch0;
        float so1[4];
        {
            const unsigned short* sh_ = p.s1h[pi];
            const unsigned short* sl_ = p.s1l[pi];
            const sh8* Ahh = (const sh8*)sh_ + (size_t)bA * 64;
            const sh8* Ahl = (const sh8*)sl_ + (size_t)bA * 64;
            sh8 hh[16], hl[16];
            #pragma unroll
            for (int ks = 0; ks < 16; ++ks) { hh[ks] = Ahh[ks * 4 + quad]; hl[ks] = Ahl[ks * 4 + quad]; }
            #pragma unroll
            for (int r = 0; r < 4; ++r) {
                size_t ix = (size_t)(bD + r) * HSZ + h;
                so1[r] = bf2f(sh_[ix]) + bf2f(sl_[ix]);
            }
            #pragma unroll
            for (int ks = 0; ks < 16; ++ks) {
                const int fo = (ks * 4 + quad) * 8;
                sh8 whr = *(const sh8*)&W[6][m][fo];
                sh8 whz = *(const sh8*)&W[7][m][fo];
                sh8 whn = *(const sh8*)&W[8][m][fo];
                ch0 = MFMA(hh[ks], whr, ch0); ch0 = MFMA(hl[ks], whr, ch0);
                ch1 = MFMA(hh[ks], whz, ch1); ch1 = MFMA(hl[ks], whz, ch1);
                ch2 = MFMA(hh[ks], whn, ch2); ch2 = MFMA(hl[ks], whn, ch2);
            }
        }
        gbar_wait(gb, bno, fast);             // wait + __syncthreads + L1 inv

        // ---------- exposed B: gi2 = s0_new @ w_ih2^T (needs bar1), GRU2 + fc ---------
        {
            const sh8* Aih = (const sh8*)p.s0h[po] + (size_t)bA * 64;
            const sh8* Ail = (const sh8*)p.s0l[po] + (size_t)bA * 64;

            sh8 ih[16], il[16];
            #pragma unroll
            for (int ks = 0; ks < 16; ++ks) { ih[ks] = Aih[ks * 4 + quad]; il[ks] = Ail[ks * 4 + quad]; }
            f4 ci0 = {0.f,0.f,0.f,0.f}, ci1 = ci0, ci2 = ci0;
            #pragma unroll
            for (int ks = 0; ks < 16; ++ks) {
                const int fo = (ks * 4 + quad) * 8;
                sh8 wir = *(const sh8*)&W[3][m][fo];
                sh8 wiz = *(const sh8*)&W[4][m][fo];
                sh8 win = *(const sh8*)&W[5][m][fo];
                ci0 = MFMA(ih[ks], wir, ci0); ci0 = MFMA(il[ks], wir, ci0);
                ci1 = MFMA(ih[ks], wiz, ci1); ci1 = MFMA(il[ks], wiz, ci1);
                ci2 = MFMA(ih[ks], win, ci2); ci2 = MFMA(il[ks], win, ci2);
            }
            unsigned short* oh = p.s1h[po];
            unsigned short* ol = p.s1l[po];
            #pragma unroll
            for (int r = 0; r < 4; ++r) {
                int b = bD + r;
                float rr = sigm(ci0[r] + bi2v0 + ch0[r] + bh2v0);
                float zz = sigm(ci1[r] + bi2v1 + ch1[r] + bh2v1);
                float nn = tanh_(ci2[r] + bi2v2 + rr * (ch2[r] + bh2v2));
                size_t ix = (size_t)b * HSZ + h;
                float sn = (1.f - zz) * nn + zz * so1[r];
                unsigned short u = f2bf(sn);
                oh[ix] = u; ol[ix] = f2bf(sn - bf2f(u));
                float c = sn * wfcv;
                c += __shfl_xor(c, 1); c += __shfl_xor(c, 2);
                c += __shfl_xor(c, 4); c += __shfl_xor(c, 8);
                if (m == 0) {
                    if (fast) __hip_atomic_fetch_add(&p.accT[t * BSZ + b], c, RLX, WGRP);
                    else      atomicAdd(&p.accT[t * BSZ + b], c);
                }
            }
        }
        ++bno; gbar(gb, hx, bno, fast);       // bar2: monolithic, identical to R3
    }

    // ---------- epilogue: group-local out write (follows final gbar + L1-inv) ----------
    {
        const int r = hx;
        for (int e = tid; e < 512; e += NT) {
            int idx = r * 512 + e;
            int bl = idx >> 8, t = idx & 255;
            int b = by * 64 + bl;
            float av = fast ? p.accT[t * BSZ + b]
                            : __hip_atomic_load(&p.accT[t * BSZ + b], RLX, AGENT);
            p.out[(size_t)b * 256 + t] = fmaxf(av + bfc, 0.f);
        }
    }
}

extern "C" void kernel_launch(void* const* d_in, const int* in_sizes, int n_in,
                              void* d_out, int out_size, void* d_ws, size_t ws_size,
                              hipStream_t stream)
{
    (void)in_sizes; (void)n_in; (void)out_size; (void)ws_size;
    P p;
    p.z1    = (const float*)d_in[0];
    p.y     = (const float*)d_in[1];
    p.x     = (const float*)d_in[2];
    p.h1    = (const float*)d_in[3];
    p.w_ih1 = (const float*)d_in[4];
    p.w_hh1 = (const float*)d_in[5];
    p.b_ih1 = (const float*)d_in[6];
    p.b_hh1 = (const float*)d_in[7];
    p.w_ih2 = (const float*)d_in[8];
    p.w_hh2 = (const float*)d_in[9];
    p.b_ih2 = (const float*)d_in[10];
    p.b_hh2 = (const float*)d_in[11];
    p.w_fc  = (const float*)d_in[12];
    p.b_fc  = (const float*)d_in[13];

    unsigned short* ws = (unsigned short*)d_ws;
    size_t off = 0;
    p.wb1 = ws + off; off += (size_t)G3H * HSZ;
    p.wb2 = ws + off; off += (size_t)G3H * HSZ;
    p.wbI = ws + off; off += (size_t)G3H * HSZ;
    p.giy = ws + off; off += (size_t)BSZ * G3H;
    for (int i = 0; i < 2; ++i) { p.s0h[i] = ws + off; off += (size_t)BSZ * HSZ; }
    for (int i = 0; i < 2; ++i) { p.s0l[i] = ws + off; off += (size_t)BSZ * HSZ; }
    for (int i = 0; i < 2; ++i) { p.s1h[i] = ws + off; off += (size_t)BSZ * HSZ; }
    for (int i = 0; i < 2; ++i) { p.s1l[i] = ws + off; off += (size_t)BSZ * HSZ; }
    p.accT  = (float*)(ws + off);    off += (size_t)LSEQ * BSZ * 2;
    p.bar   = (unsigned*)(ws + off); off += 8 * 512 * 2;
    p.claim = (unsigned*)(ws + off);
    p.out   = (float*)d_out;

    init_k<<<dim3(1024), dim3(256), 0, stream>>>(p);

    void* args[] = { &p };
    hipLaunchCooperativeKernel((const void*)rnn_kernel, dim3(NB), dim3(NT), args, 0, stream);
}

// Round 6
// 4279.773 us; speedup vs baseline: 1.3292x; 1.0193x over previous
//
#include <hip/hip_runtime.h>
#include <hip/hip_cooperative_groups.h>
#include <math.h>

namespace cg = cooperative_groups;

#define NB   256      // persistent blocks (1 per CU)
#define NT   256      // threads per block (4 waves)
#define BSZ  512      // batch
#define HSZ  512      // hidden
#define LSEQ 256      // sequence length
#define G3H  1536

typedef __attribute__((ext_vector_type(8))) short sh8;   // 8 bf16 = one MFMA frag
typedef __attribute__((ext_vector_type(4))) float f4;    // MFMA acc

#define MFMA(a,b,c) __builtin_amdgcn_mfma_f32_16x16x32_bf16((a),(b),(c),0,0,0)
#define AGENT __HIP_MEMORY_SCOPE_AGENT
#define WGRP  __HIP_MEMORY_SCOPE_WORKGROUP
#define RLX   __ATOMIC_RELAXED

__device__ __forceinline__ float bf2f(unsigned short u) {
    union { unsigned int i; float f; } v; v.i = ((unsigned int)u) << 16; return v.f;
}
__device__ __forceinline__ unsigned short f2bf(float f) {
    union { float f; unsigned int i; } v; v.f = f;
    unsigned int r = v.i + 0x7fffu + ((v.i >> 16) & 1u);   // RNE
    return (unsigned short)(r >> 16);
}
__device__ __forceinline__ float sigm(float v) { return 1.f / (1.f + __expf(-v)); }
__device__ __forceinline__ float tanh_(float v) { return 1.f - 2.f / (1.f + __expf(2.f * v)); }

__device__ __forceinline__ int xcc_id() {
    int x;
    asm volatile("s_getreg_b32 %0, hwreg(HW_REG_XCC_ID)" : "=s"(x));
    return x & 7;
}

struct P {
    const float *z1, *y, *x, *h1;
    const float *w_ih1, *w_hh1, *b_ih1, *b_hh1;
    const float *w_ih2, *w_hh2, *b_ih2, *b_hh2;
    const float *w_fc, *b_fc;
    unsigned short *wb1, *wb2, *wbI;        // bf16 weights [1536][512]
    unsigned short *giy;                     // bf16 [512][1536]
    unsigned short *s0h[2], *s0l[2];         // bf16 hi/lo state ping-pong [512][512]
    unsigned short *s1h[2], *s1l[2];
    float *accT;                             // [256][512]
    unsigned *bar;                           // 8 groups x 512 u32 barrier region
    unsigned *claim;                         // 8 per-XCD slot counters
    float *out;                              // [512][256]
};

// ---------------- init kernel (kernel-boundary flush publishes all of this) ------
__global__ __launch_bounds__(256) void init_k(P p)
{
    int gt = blockIdx.x * 256 + threadIdx.x;
    int stride = gridDim.x * 256;
    for (int i = gt; i < G3H * HSZ; i += stride) {
        p.wb1[i] = f2bf(p.w_hh1[i]);
        p.wb2[i] = f2bf(p.w_hh2[i]);
        p.wbI[i] = f2bf(p.w_ih2[i]);
    }
    for (int i = gt; i < BSZ * HSZ; i += stride) {
        int b = i >> 9, hh = i & 511;
        float v0 = (hh < 385) ? p.z1[b * 385 + hh] : p.y[b * 127 + (hh - 385)];
        unsigned short u = f2bf(v0);
        p.s0h[0][i] = u; p.s0l[0][i] = f2bf(v0 - bf2f(u));
        float v1 = p.h1[i];
        u = f2bf(v1);
        p.s1h[0][i] = u; p.s1l[0][i] = f2bf(v1 - bf2f(u));
    }
    for (int i = gt; i < LSEQ * BSZ; i += stride) p.accT[i] = 0.f;
    for (int i = gt; i < 8 * 512; i += stride) p.bar[i] = 0u;
    for (int i = gt; i < 8; i += stride) p.claim[i] = 0u;
    for (int i = gt; i < BSZ * G3H; i += stride) {
        int b = i / G3H, j = i - b * G3H;
        float a = p.b_ih1[j];
        const float* yr = p.y + b * 127;
        const float* wr = p.w_ih1 + j * 128 + 1;
        #pragma unroll 4
        for (int k = 0; k < 127; ++k) a += yr[k] * wr[k];
        p.giy[i] = f2bf(a);
    }
}

// Batched scan of all 8 sub-lines in ONE round-trip. Each op is the R7-proven
// poll_rmw form (global_atomic_add vdst, vaddr, 0 sc0 — returns old, executes
// at XCD L2, never stale-L1). Proven sound in R3 (passed, -1.37ms).
__device__ __forceinline__ bool scan8p(unsigned* l0, unsigned* l1, unsigned* l2, unsigned* l3,
                                       unsigned* l4, unsigned* l5, unsigned* l6, unsigned* l7,
                                       unsigned tgt)
{
    unsigned r0, r1, r2, r3, r4, r5, r6, r7;
    unsigned z = 0;
    asm volatile(
        "global_atomic_add %0, %8, %16, off sc0\n\t"
        "global_atomic_add %1, %9, %16, off sc0\n\t"
        "global_atomic_add %2, %10, %16, off sc0\n\t"
        "global_atomic_add %3, %11, %16, off sc0\n\t"
        "global_atomic_add %4, %12, %16, off sc0\n\t"
        "global_atomic_add %5, %13, %16, off sc0\n\t"
        "global_atomic_add %6, %14, %16, off sc0\n\t"
        "global_atomic_add %7, %15, %16, off sc0\n\t"
        "s_waitcnt vmcnt(0)"
        : "=&v"(r0), "=&v"(r1), "=&v"(r2), "=&v"(r3),
          "=&v"(r4), "=&v"(r5), "=&v"(r6), "=&v"(r7)
        : "v"(l0), "v"(l1), "v"(l2), "v"(l3),
          "v"(l4), "v"(l5), "v"(l6), "v"(l7), "v"(z)
        : "memory");
    return (r0 >= tgt) & (r1 >= tgt) & (r2 >= tgt) & (r3 >= tgt)
         & (r4 >= tgt) & (r5 >= tgt) & (r6 >= tgt) & (r7 >= tgt);
}

// Split barrier pieces. Semantics proven in R3/R5.
// Caller of gbar_arrive must have executed __syncthreads() first (drains
// vmcnt(0) per wave -> stores committed in XCD L2 before arrival visible).
__device__ __forceinline__ void gbar_arrive(unsigned* gb, int hx, bool fast)
{
    if (threadIdx.x == 0) {
        if (fast) __hip_atomic_fetch_add(gb + (hx & 7) * 32, 1u, RLX, WGRP);
        else      __hip_atomic_fetch_add(gb, 1u, __ATOMIC_RELEASE, AGENT);
    }
}
__device__ __forceinline__ void gbar_wait(unsigned* gb, unsigned bno, bool fast)
{
    if (threadIdx.x == 0) {
        if (fast) {
            unsigned tgt = 4u * bno;
            long g = 0;
            while (!scan8p(gb, gb + 32, gb + 64, gb + 96,
                           gb + 128, gb + 160, gb + 192, gb + 224, tgt)) {
                __builtin_amdgcn_s_sleep(1);
                if (++g > (1L << 24)) break;
            }
        } else {
            long g = 0;
            while (__hip_atomic_load(gb, RLX, AGENT) < 32u * bno) {
                __builtin_amdgcn_s_sleep(1);
                if (++g > (1L << 27)) break;
            }
            __builtin_amdgcn_fence(__ATOMIC_ACQUIRE, "agent");
        }
    }
    __syncthreads();
    if (fast) {
        // invalidate this CU's L1 so post-barrier loads see the group's L2 data
        asm volatile("buffer_inv sc0\n\ts_waitcnt vmcnt(0)" ::: "memory");
    }
}

__global__ __launch_bounds__(NT, 1) void rnn_kernel(P p)
{
    // ALL 9 weight matrices for this block's 16 h-cols live in LDS (146 KB):
    // 0-2: w_hh1 r/z/n   3-5: w_ih2 r/z/n   6-8: w_hh2 r/z/n
    __shared__ __align__(16) unsigned short W[9][16][520];
    __shared__ int s_xcd, s_slot;

    cg::grid_group grid = cg::this_grid();
    const int tid  = threadIdx.x;
    const int bid  = blockIdx.x;

    // ---- runtime XCD-local group formation ----
    if (tid == 0) {
        int x = xcc_id();
        s_xcd = x;
        s_slot = (int)__hip_atomic_fetch_add(&p.claim[x], 1u, RLX, AGENT);
    }
    grid.sync();   // one-time full-coherence rendezvous (claims all visible)

    bool fast = true;
    #pragma unroll
    for (int x = 0; x < 8; ++x)
        fast = fast && (__hip_atomic_load(&p.claim[x], RLX, AGENT) == 32u);

    const int by = fast ? s_xcd  : (bid >> 5);   // batch group (8)
    const int hx = fast ? s_slot : (bid & 31);   // h tile within group (32)

    const int lane = tid & 63, w = tid >> 6;
    const int m = lane & 15, quad = lane >> 4;
    const int h0 = hx * 16, b0 = by * 64 + w * 16;
    const int h  = h0 + m;
    const int bA = b0 + m;
    const int bD = b0 + quad * 4;
    unsigned* gb = p.bar + by * 512;

    // stage all 9 weight matrices into LDS
    for (int c = tid; c < 9 * 1024; c += NT) {
        int mat = c >> 10, rem = c & 1023;
        int lc = rem >> 6, ch = rem & 63;
        const unsigned short* base =
            (mat < 3) ? (p.wb1 + (size_t)(mat * HSZ + h0 + lc) * HSZ)
          : (mat < 6) ? (p.wbI + (size_t)((mat - 3) * HSZ + h0 + lc) * HSZ)
                      : (p.wb2 + (size_t)((mat - 6) * HSZ + h0 + lc) * HSZ);
        *(sh8*)&W[mat][lc][ch * 8] = *((const sh8*)base + ch);
    }
    __syncthreads();

    const float bfc = p.b_fc[0];
    const int hq0 = h, hq1 = HSZ + h, hq2 = 2 * HSZ + h;
    const float bh1v0 = p.b_hh1[hq0], bh1v1 = p.b_hh1[hq1], bh1v2 = p.b_hh1[hq2];
    const float bi2v0 = p.b_ih2[hq0], bi2v1 = p.b_ih2[hq1], bi2v2 = p.b_ih2[hq2];
    const float bh2v0 = p.b_hh2[hq0], bh2v1 = p.b_hh2[hq1], bh2v2 = p.b_hh2[hq2];
    const float w0c0 = p.w_ih1[(size_t)hq0 * 128];
    const float w0c1 = p.w_ih1[(size_t)hq1 * 128];
    const float w0c2 = p.w_ih1[(size_t)hq2 * 128];
    const float wfcv = p.w_fc[h];

    float gyv[4][3];
    #pragma unroll
    for (int r = 0; r < 4; ++r) {
        gyv[r][0] = bf2f(p.giy[(size_t)(bD + r) * G3H + hq0]);
        gyv[r][1] = bf2f(p.giy[(size_t)(bD + r) * G3H + hq1]);
        gyv[r][2] = bf2f(p.giy[(size_t)(bD + r) * G3H + hq2]);
    }

    // ---- prologue prefetch: phase-A inputs for t=0 from s0[0] (init_k published) ----
    sh8 ah[16], al[16];
    float so0[4];
    {
        const sh8* Ah = (const sh8*)p.s0h[0] + (size_t)bA * 64;
        const sh8* Al = (const sh8*)p.s0l[0] + (size_t)bA * 64;
        #pragma unroll
        for (int ks = 0; ks < 16; ++ks) { ah[ks] = Ah[ks * 4 + quad]; al[ks] = Al[ks * 4 + quad]; }
        #pragma unroll
        for (int r = 0; r < 4; ++r) {
            size_t ix = (size_t)(bD + r) * HSZ + h;
            so0[r] = bf2f(p.s0h[0][ix]) + bf2f(p.s0l[0][ix]);
        }
    }

    unsigned bno = 0;

    #pragma clang loop unroll(disable)
    for (int t = 0; t < LSEQ; ++t) {
        const int pi = t & 1, po = pi ^ 1;
        (void)pi;

        // ---------- phase A: gh1 = s0 @ w_hh1^T (frags PREFETCHED), GRU1 -> s0_new ----
        {
            // issue accT loads first so their L2 RTT hides under the MFMA loop
            float outv[4];
            if (t == 0) {
                #pragma unroll
                for (int r = 0; r < 4; ++r) outv[r] = p.x[bD + r];
            } else {
                #pragma unroll
                for (int r = 0; r < 4; ++r) {
                    float av = fast ? p.accT[(size_t)(t - 1) * BSZ + bD + r]
                                    : __hip_atomic_load(&p.accT[(size_t)(t - 1) * BSZ + bD + r], RLX, AGENT);
                    outv[r] = fmaxf(av + bfc, 0.f);
                }
            }
            f4 a0 = {0.f,0.f,0.f,0.f}, a1 = a0, a2 = a0;
            #pragma unroll
            for (int ks = 0; ks < 16; ++ks) {
                const int fo = (ks * 4 + quad) * 8;
                sh8 w_r = *(const sh8*)&W[0][m][fo];
                sh8 w_z = *(const sh8*)&W[1][m][fo];
                sh8 w_n = *(const sh8*)&W[2][m][fo];
                a0 = MFMA(ah[ks], w_r, a0); a0 = MFMA(al[ks], w_r, a0);
                a1 = MFMA(ah[ks], w_z, a1); a1 = MFMA(al[ks], w_z, a1);
                a2 = MFMA(ah[ks], w_n, a2); a2 = MFMA(al[ks], w_n, a2);
            }
            unsigned short* oh = p.s0h[po];
            unsigned short* ol = p.s0l[po];
            #pragma unroll
            for (int r = 0; r < 4; ++r) {
                int b = bD + r;
                float o  = outv[r];
                float rr = sigm(gyv[r][0] + o * w0c0 + a0[r] + bh1v0);
                float zz = sigm(gyv[r][1] + o * w0c1 + a1[r] + bh1v1);
                float nn = tanh_(gyv[r][2] + o * w0c2 + rr * (a2[r] + bh1v2));
                float sn = (1.f - zz) * nn + zz * so0[r];
                size_t ix = (size_t)b * HSZ + h;
                unsigned short u = f2bf(sn);
                oh[ix] = u; ol[ix] = f2bf(sn - bf2f(u));
            }
        }
        ++bno;
        __syncthreads();                      // drains vmcnt(0): s0_new in XCD L2
        gbar_arrive(gb, hx, fast);

        // ---------- bar1 window: gh2 = s1[pi] @ w_hh2^T (published at bar2(t-1)) -----
        f4 ch0 = {0.f,0.f,0.f,0.f}, ch1 = ch0, ch2 = ch0;
        float so1[4];
        {
            const unsigned short* sh_ = p.s1h[pi];
            const unsigned short* sl_ = p.s1l[pi];
            const sh8* Ahh = (const sh8*)sh_ + (size_t)bA * 64;
            const sh8* Ahl = (const sh8*)sl_ + (size_t)bA * 64;
            sh8 hh[16], hl[16];
            #pragma unroll
            for (int ks = 0; ks < 16; ++ks) { hh[ks] = Ahh[ks * 4 + quad]; hl[ks] = Ahl[ks * 4 + quad]; }
            #pragma unroll
            for (int r = 0; r < 4; ++r) {
                size_t ix = (size_t)(bD + r) * HSZ + h;
                so1[r] = bf2f(sh_[ix]) + bf2f(sl_[ix]);
            }
            #pragma unroll
            for (int ks = 0; ks < 16; ++ks) {
                const int fo = (ks * 4 + quad) * 8;
                sh8 whr = *(const sh8*)&W[6][m][fo];
                sh8 whz = *(const sh8*)&W[7][m][fo];
                sh8 whn = *(const sh8*)&W[8][m][fo];
                ch0 = MFMA(hh[ks], whr, ch0); ch0 = MFMA(hl[ks], whr, ch0);
                ch1 = MFMA(hh[ks], whz, ch1); ch1 = MFMA(hl[ks], whz, ch1);
                ch2 = MFMA(hh[ks], whn, ch2); ch2 = MFMA(hl[ks], whn, ch2);
            }
        }
        gbar_wait(gb, bno, fast);             // wait + __syncthreads + L1 inv

        // ---------- exposed B: gi2 = s0_new @ w_ih2^T (needs bar1), GRU2 + fc ---------
        {
            const sh8* Aih = (const sh8*)p.s0h[po] + (size_t)bA * 64;
            const sh8* Ail = (const sh8*)p.s0l[po] + (size_t)bA * 64;

            sh8 ih[16], il[16];
            #pragma unroll
            for (int ks = 0; ks < 16; ++ks) { ih[ks] = Aih[ks * 4 + quad]; il[ks] = Ail[ks * 4 + quad]; }
            f4 ci0 = {0.f,0.f,0.f,0.f}, ci1 = ci0, ci2 = ci0;
            #pragma unroll
            for (int ks = 0; ks < 16; ++ks) {
                const int fo = (ks * 4 + quad) * 8;
                sh8 wir = *(const sh8*)&W[3][m][fo];
                sh8 wiz = *(const sh8*)&W[4][m][fo];
                sh8 win = *(const sh8*)&W[5][m][fo];
                ci0 = MFMA(ih[ks], wir, ci0); ci0 = MFMA(il[ks], wir, ci0);
                ci1 = MFMA(ih[ks], wiz, ci1); ci1 = MFMA(il[ks], wiz, ci1);
                ci2 = MFMA(ih[ks], win, ci2); ci2 = MFMA(il[ks], win, ci2);
            }
            unsigned short* oh = p.s1h[po];
            unsigned short* ol = p.s1l[po];
            #pragma unroll
            for (int r = 0; r < 4; ++r) {
                int b = bD + r;
                float rr = sigm(ci0[r] + bi2v0 + ch0[r] + bh2v0);
                float zz = sigm(ci1[r] + bi2v1 + ch1[r] + bh2v1);
                float nn = tanh_(ci2[r] + bi2v2 + rr * (ch2[r] + bh2v2));
                size_t ix = (size_t)b * HSZ + h;
                float sn = (1.f - zz) * nn + zz * so1[r];
                unsigned short u = f2bf(sn);
                oh[ix] = u; ol[ix] = f2bf(sn - bf2f(u));
                float c = sn * wfcv;
                c += __shfl_xor(c, 1); c += __shfl_xor(c, 2);
                c += __shfl_xor(c, 4); c += __shfl_xor(c, 8);
                if (m == 0) {
                    if (fast) __hip_atomic_fetch_add(&p.accT[t * BSZ + b], c, RLX, WGRP);
                    else      atomicAdd(&p.accT[t * BSZ + b], c);
                }
            }
        }
        ++bno;
        __syncthreads();                      // drains vmcnt(0): s1_new + accT in L2
        gbar_arrive(gb, hx, fast);

        // ---------- bar2 window: prefetch phase-A(t+1) inputs from s0[po] -------------
        // s0[po(t)] was fully published at bar1(t) (we're past bar1(t)-wait+inv), and
        // these lines are L1-fresh (exposed-B just read them). Next writer of this
        // buffer is epiA(t+2), gated behind bar2(t+1) -- i.e. after our phase-A(t+1)
        // use. Values ride in VGPRs (ah/al/so0) across the wait; the buffer_inv only
        // clobbers memory visibility, not registers.
        {
            const sh8* Ah = (const sh8*)p.s0h[po] + (size_t)bA * 64;
            const sh8* Al = (const sh8*)p.s0l[po] + (size_t)bA * 64;
            #pragma unroll
            for (int ks = 0; ks < 16; ++ks) { ah[ks] = Ah[ks * 4 + quad]; al[ks] = Al[ks * 4 + quad]; }
            #pragma unroll
            for (int r = 0; r < 4; ++r) {
                size_t ix = (size_t)(bD + r) * HSZ + h;
                so0[r] = bf2f(p.s0h[po][ix]) + bf2f(p.s0l[po][ix]);
            }
        }
        gbar_wait(gb, bno, fast);             // wait + __syncthreads + L1 inv
    }

    // ---------- epilogue: group-local out write (follows final bar2 + L1-inv) ----------
    {
        const int r = hx;
        for (int e = tid; e < 512; e += NT) {
            int idx = r * 512 + e;
            int bl = idx >> 8, t = idx & 255;
            int b = by * 64 + bl;
            float av = fast ? p.accT[t * BSZ + b]
                            : __hip_atomic_load(&p.accT[t * BSZ + b], RLX, AGENT);
            p.out[(size_t)b * 256 + t] = fmaxf(av + bfc, 0.f);
        }
    }
}

extern "C" void kernel_launch(void* const* d_in, const int* in_sizes, int n_in,
                              void* d_out, int out_size, void* d_ws, size_t ws_size,
                              hipStream_t stream)
{
    (void)in_sizes; (void)n_in; (void)out_size; (void)ws_size;
    P p;
    p.z1    = (const float*)d_in[0];
    p.y     = (const float*)d_in[1];
    p.x     = (const float*)d_in[2];
    p.h1    = (const float*)d_in[3];
    p.w_ih1 = (const float*)d_in[4];
    p.w_hh1 = (const float*)d_in[5];
    p.b_ih1 = (const float*)d_in[6];
    p.b_hh1 = (const float*)d_in[7];
    p.w_ih2 = (const float*)d_in[8];
    p.w_hh2 = (const float*)d_in[9];
    p.b_ih2 = (const float*)d_in[10];
    p.b_hh2 = (const float*)d_in[11];
    p.w_fc  = (const float*)d_in[12];
    p.b_fc  = (const float*)d_in[13];

    unsigned short* ws = (unsigned short*)d_ws;
    size_t off = 0;
    p.wb1 = ws + off; off += (size_t)G3H * HSZ;
    p.wb2 = ws + off; off += (size_t)G3H * HSZ;
    p.wbI = ws + off; off += (size_t)G3H * HSZ;
    p.giy = ws + off; off += (size_t)BSZ * G3H;
    for (int i = 0; i < 2; ++i) { p.s0h[i] = ws + off; off += (size_t)BSZ * HSZ; }
    for (int i = 0; i < 2; ++i) { p.s0l[i] = ws + off; off += (size_t)BSZ * HSZ; }
    for (int i = 0; i < 2; ++i) { p.s1h[i] = ws + off; off += (size_t)BSZ * HSZ; }
    for (int i = 0; i < 2; ++i) { p.s1l[i] = ws + off; off += (size_t)BSZ * HSZ; }
    p.accT  = (float*)(ws + off);    off += (size_t)LSEQ * BSZ * 2;
    p.bar   = (unsigned*)(ws + off); off += 8 * 512 * 2;
    p.claim = (unsigned*)(ws + off);
    p.out   = (float*)d_out;

    init_k<<<dim3(1024), dim3(256), 0, stream>>>(p);

    void* args[] = { &p };
    hipLaunchCooperativeKernel((const void*)rnn_kernel, dim3(NB), dim3(NT), args, 0, stream);
}